// Round 1
// baseline (289.112 us; speedup 1.0000x reference)
//
#include <hip/hip_runtime.h>
#include <stdint.h>

typedef unsigned short u16;
typedef unsigned int u32;
typedef short v8s __attribute__((ext_vector_type(8)));
typedef float v4f __attribute__((ext_vector_type(4)));

#define N_NODES 8192
#define N_EDGES 524288
#define DFEAT 256
#define PADC 160   // per-receiver bucket capacity; deg ~ Bin(524288, 2^-13): mean 64, sigma 8

static __device__ __forceinline__ float bflo(u32 u) { return __uint_as_float(u << 16); }
static __device__ __forceinline__ float bfhi(u32 u) { return __uint_as_float(u & 0xffff0000u); }
static __device__ __forceinline__ u16 f2bf(float f) {
    u32 u = __float_as_uint(f);
    return (u16)((u + 0x7fffu + ((u >> 16) & 1u)) >> 16);
}

// ---- K1 (tiny): W transpose -> bf16 wt (48 blocks) + cnt zeroing (8 blocks) ----
__global__ void prep_small(const float* __restrict__ w0, const float* __restrict__ w1,
                           const float* __restrict__ w2, u16* __restrict__ wt,
                           int* __restrict__ cnt) {
    int b = blockIdx.x;
    if (b < 48) {
        __shared__ u16 t[64][65];
        int region = b >> 4, tile = b & 15;
        int k0 = (tile >> 2) * 64, n0 = (tile & 3) * 64;
        const float* w = (region == 0) ? w0 : ((region == 1) ? w1 : w2);
        int tx = threadIdx.x & 63, ty = threadIdx.x >> 6;
#pragma unroll
        for (int it = 0; it < 16; it++) {
            int row = it * 4 + ty;
            t[row][tx] = f2bf(w[(k0 + row) * 256 + n0 + tx]);
        }
        __syncthreads();
        u16* o = wt + region * 65536;
#pragma unroll
        for (int it = 0; it < 16; it++) {
            int row = it * 4 + ty;
            o[(n0 + row) * 256 + k0 + tx] = t[tx][row];
        }
    } else {
        int i = ((b - 48) * 256 + threadIdx.x) * 4;
        *(int4*)(cnt + i) = make_int4(0, 0, 0, 0);
    }
}

// ---- K2: scatter (blocks 0..511, overlapped) + bf16 MFMA GEMM from f32 h (blocks 512..2047) ----
__global__ __launch_bounds__(256) void main_mid(
    const float* __restrict__ h, const u16* __restrict__ wt,
    const float* __restrict__ bq, const float* __restrict__ bk,
    const int* __restrict__ recv, const int* __restrict__ send,
    u16* __restrict__ hproj, u16* __restrict__ qbuf, u16* __restrict__ kbuf,
    int* __restrict__ cnt, u16* __restrict__ es) {
    int b = blockIdx.x;
    if (b < 512) {
        // padded-bucket scatter, 4 edges/thread
        int e = (b * 256 + threadIdx.x) * 4;
        int4 rv = *(const int4*)(recv + e);
        int4 sv = *(const int4*)(send + e);
        int r, s, pos;
        r = rv.x; s = sv.x; pos = atomicAdd(&cnt[r], 1); if (pos < PADC) es[r * PADC + pos] = (u16)s;
        r = rv.y; s = sv.y; pos = atomicAdd(&cnt[r], 1); if (pos < PADC) es[r * PADC + pos] = (u16)s;
        r = rv.z; s = sv.z; pos = atomicAdd(&cnt[r], 1); if (pos < PADC) es[r * PADC + pos] = (u16)s;
        r = rv.w; s = sv.w; pos = atomicAdd(&cnt[r], 1); if (pos < PADC) es[r * PADC + pos] = (u16)s;
    } else {
        int g = b - 512;
        int wave = threadIdx.x >> 6, lane = threadIdx.x & 63;
        int lm = lane & 15, lq = lane >> 4;
        int bx = g & 127, by = g >> 7;          // by in [0,12)
        int m0 = bx * 64 + wave * 16;
        int region = by >> 2, n0b = (by & 3) * 64;
        const u16* wtr = wt + region * 65536;

        v4f acc[4];
#pragma unroll
        for (int nt = 0; nt < 4; nt++) acc[nt] = (v4f){0.f, 0.f, 0.f, 0.f};

        const float* arow = h + (m0 + lm) * 256 + lq * 8;
#pragma unroll
        for (int k0 = 0; k0 < 256; k0 += 32) {
            float4 f0 = *(const float4*)(arow + k0);
            float4 f1 = *(const float4*)(arow + k0 + 4);
            v8s a;
            a[0] = (short)f2bf(f0.x); a[1] = (short)f2bf(f0.y);
            a[2] = (short)f2bf(f0.z); a[3] = (short)f2bf(f0.w);
            a[4] = (short)f2bf(f1.x); a[5] = (short)f2bf(f1.y);
            a[6] = (short)f2bf(f1.z); a[7] = (short)f2bf(f1.w);
#pragma unroll
            for (int nt = 0; nt < 4; nt++) {
                v8s bb = *(const v8s*)(wtr + (n0b + nt * 16 + lm) * 256 + k0 + lq * 8);
                acc[nt] = __builtin_amdgcn_mfma_f32_16x16x32_bf16(a, bb, acc[nt], 0, 0, 0);
            }
        }
        u16* outp = (region == 0) ? hproj : ((region == 1) ? qbuf : kbuf);
        const float* bias = (region == 1) ? bq : ((region == 2) ? bk : nullptr);
#pragma unroll
        for (int nt = 0; nt < 4; nt++) {
            int nn = n0b + nt * 16 + lm;
            float bv = bias ? bias[nn] : 0.f;
#pragma unroll
            for (int i = 0; i < 4; i++) {
                int m = m0 + lq * 4 + i;
                outp[m * 256 + nn] = f2bf(acc[nt][i] + bv);
            }
        }
    }
}

// ---- K3: edge kernel, VALU dot + butterfly reduce (no MFMA, no LDS, no fence) ----
// wave per receiver; half-wave (32 lanes x 8 cols = 256 cols) owns one edge at a time.
// half 0 takes edges [c0, c0+8), half 1 [c0+8, c0+16) of the padded bucket.
#define DOT_AGG(SW, T) do {                                                   \
    int s_ = (int)(((SW) >> (((T) & 1) * 16)) & 0xffffu);                     \
    int off_ = s_ * 256 + cb;                                                 \
    uint4 qv_ = *(const uint4*)(qbuf + off_);                                 \
    uint4 hv_ = *(const uint4*)(hpb + off_);                                  \
    float p_ = kr0 * bflo(qv_.x) + kr1 * bfhi(qv_.x)                          \
             + kr2 * bflo(qv_.y) + kr3 * bfhi(qv_.y)                          \
             + kr4 * bflo(qv_.z) + kr5 * bfhi(qv_.z)                          \
             + kr6 * bflo(qv_.w) + kr7 * bfhi(qv_.w);                         \
    p_ += __shfl_xor(p_, 1, 32);                                              \
    p_ += __shfl_xor(p_, 2, 32);                                              \
    p_ += __shfl_xor(p_, 4, 32);                                              \
    p_ += __shfl_xor(p_, 8, 32);                                              \
    p_ += __shfl_xor(p_, 16, 32);                                             \
    a0 += p_ * bflo(hv_.x); a1 += p_ * bfhi(hv_.x);                           \
    a2 += p_ * bflo(hv_.y); a3 += p_ * bfhi(hv_.y);                           \
    a4 += p_ * bflo(hv_.z); a5 += p_ * bfhi(hv_.z);                           \
    a6 += p_ * bflo(hv_.w); a7 += p_ * bfhi(hv_.w);                           \
} while (0)

__global__ __launch_bounds__(256, 8) void edge_fused(
    const u16* __restrict__ qbuf, const u16* __restrict__ kbuf,
    const u16* __restrict__ hpb, const int* __restrict__ cnt,
    const u16* __restrict__ es, float* __restrict__ out) {
    int wave = threadIdx.x >> 6, lane = threadIdx.x & 63;
    int r = blockIdx.x * 4 + wave;
    int lh = lane & 31, half = lane >> 5;
    int cb = lh * 8;
    int n = min(cnt[r], PADC);
    int base = r * PADC;

    // unpack k[r] segment (this lane's 8 columns), hoisted
    uint4 kv = *(const uint4*)(kbuf + r * 256 + cb);
    float kr0 = bflo(kv.x), kr1 = bfhi(kv.x), kr2 = bflo(kv.y), kr3 = bfhi(kv.y),
          kr4 = bflo(kv.z), kr5 = bfhi(kv.z), kr6 = bflo(kv.w), kr7 = bfhi(kv.w);

    float a0 = 0.f, a1 = 0.f, a2 = 0.f, a3 = 0.f,
          a4 = 0.f, a5 = 0.f, a6 = 0.f, a7 = 0.f;

    // prefetched uniform sender pack: 8 u16 senders for this half's sub-tile
    uint4 sp = *(const uint4*)(es + base + half * 8);
    for (int c0 = 0; c0 < n; c0 += 16) {
        int nx = c0 + 16;
        uint4 spn = sp;
        if (nx < n) spn = *(const uint4*)(es + base + nx + half * 8);

        if (nx <= n) {
            // full tile: 8 unguarded edges per half, loads pipeline freely
            DOT_AGG(sp.x, 0); DOT_AGG(sp.x, 1);
            DOT_AGG(sp.y, 2); DOT_AGG(sp.y, 3);
            DOT_AGG(sp.z, 4); DOT_AGG(sp.z, 5);
            DOT_AGG(sp.w, 6); DOT_AGG(sp.w, 7);
        } else {
            int mrem = n - (c0 + half * 8);   // uniform per half; may be <= 0
            if (0 < mrem) DOT_AGG(sp.x, 0);
            if (1 < mrem) DOT_AGG(sp.x, 1);
            if (2 < mrem) DOT_AGG(sp.y, 2);
            if (3 < mrem) DOT_AGG(sp.y, 3);
            if (4 < mrem) DOT_AGG(sp.z, 4);
            if (5 < mrem) DOT_AGG(sp.z, 5);
            if (6 < mrem) DOT_AGG(sp.w, 6);
            if (7 < mrem) DOT_AGG(sp.w, 7);
        }
        sp = spn;
    }

    // combine halves (same columns, disjoint edge sets)
    a0 += __shfl_xor(a0, 32, 64); a1 += __shfl_xor(a1, 32, 64);
    a2 += __shfl_xor(a2, 32, 64); a3 += __shfl_xor(a3, 32, 64);
    a4 += __shfl_xor(a4, 32, 64); a5 += __shfl_xor(a5, 32, 64);
    a6 += __shfl_xor(a6, 32, 64); a7 += __shfl_xor(a7, 32, 64);

    if (half == 0) {
        float4 o0, o1;
        o0.x = fmaxf(a0, 0.f); o0.y = fmaxf(a1, 0.f);
        o0.z = fmaxf(a2, 0.f); o0.w = fmaxf(a3, 0.f);
        o1.x = fmaxf(a4, 0.f); o1.y = fmaxf(a5, 0.f);
        o1.z = fmaxf(a6, 0.f); o1.w = fmaxf(a7, 0.f);
        float* op = out + r * 256 + cb;
        *(float4*)op = o0;
        *(float4*)(op + 4) = o1;
    }
}

extern "C" void kernel_launch(void* const* d_in, const int* in_sizes, int n_in,
                              void* d_out, int out_size, void* d_ws, size_t ws_size,
                              hipStream_t stream) {
    const float* h  = (const float*)d_in[0];
    const float* W  = (const float*)d_in[1];
    const float* Wq = (const float*)d_in[2];
    const float* bq = (const float*)d_in[3];
    const float* Wk = (const float*)d_in[4];
    const float* bk = (const float*)d_in[5];
    const int* senders   = (const int*)d_in[6];
    const int* receivers = (const int*)d_in[7];
    float* out = (float*)d_out;

    char* ws = (char*)d_ws;
    u16* wt    = (u16*)ws;                        // 3*65536*2 = 384 KB
    u16* hproj = (u16*)(ws + 393216);             // 4 MB
    u16* qbuf  = hproj + N_NODES * DFEAT;         // 4 MB
    u16* kbuf  = qbuf + N_NODES * DFEAT;          // 4 MB
    int* cnt   = (int*)(kbuf + N_NODES * DFEAT);  // 32 KB
    u16* es    = (u16*)(cnt + N_NODES);           // 8192*160*2 = 2.56 MB

    prep_small<<<56, 256, 0, stream>>>(W, Wq, Wk, wt, cnt);
    main_mid<<<2048, 256, 0, stream>>>(h, wt, bq, bk, receivers, senders,
                                       hproj, qbuf, kbuf, cnt, es);
    edge_fused<<<N_NODES / 4, 256, 0, stream>>>(qbuf, kbuf, hproj, cnt, es, out);
}

// Round 2
// 187.076 us; speedup vs baseline: 1.5454x; 1.5454x over previous
//
#include <hip/hip_runtime.h>
#include <stdint.h>

typedef unsigned short u16;
typedef unsigned int u32;
typedef short v8s __attribute__((ext_vector_type(8)));
typedef float v4f __attribute__((ext_vector_type(4)));

#define N_NODES 8192
#define N_EDGES 524288
#define DFEAT 256
#define PADC 160   // per-receiver bucket capacity; deg ~ Bin(524288, 2^-13): mean 64, sigma 8

static __device__ __forceinline__ float bflo(u32 u) { return __uint_as_float(u << 16); }
static __device__ __forceinline__ float bfhi(u32 u) { return __uint_as_float(u & 0xffff0000u); }
static __device__ __forceinline__ u16 f2bf(float f) {
    u32 u = __float_as_uint(f);
    return (u16)((u + 0x7fffu + ((u >> 16) & 1u)) >> 16);
}

// ---- K1 (tiny): W transpose -> bf16 wt (48 blocks) + cnt zeroing (8 blocks) ----
__global__ void prep_small(const float* __restrict__ w0, const float* __restrict__ w1,
                           const float* __restrict__ w2, u16* __restrict__ wt,
                           int* __restrict__ cnt) {
    int b = blockIdx.x;
    if (b < 48) {
        __shared__ u16 t[64][65];
        int region = b >> 4, tile = b & 15;
        int k0 = (tile >> 2) * 64, n0 = (tile & 3) * 64;
        const float* w = (region == 0) ? w0 : ((region == 1) ? w1 : w2);
        int tx = threadIdx.x & 63, ty = threadIdx.x >> 6;
#pragma unroll
        for (int it = 0; it < 16; it++) {
            int row = it * 4 + ty;
            t[row][tx] = f2bf(w[(k0 + row) * 256 + n0 + tx]);
        }
        __syncthreads();
        u16* o = wt + region * 65536;
#pragma unroll
        for (int it = 0; it < 16; it++) {
            int row = it * 4 + ty;
            o[(n0 + row) * 256 + k0 + tx] = t[tx][row];
        }
    } else {
        int i = ((b - 48) * 256 + threadIdx.x) * 4;
        *(int4*)(cnt + i) = make_int4(0, 0, 0, 0);
    }
}

// ---- K2: padded-bucket scatter (standalone this round for counter visibility) ----
__global__ __launch_bounds__(256) void scatter_k(
    const int* __restrict__ recv, const int* __restrict__ send,
    int* __restrict__ cnt, u16* __restrict__ es) {
    int e = (blockIdx.x * 256 + threadIdx.x) * 4;
    int4 rv = *(const int4*)(recv + e);
    int4 sv = *(const int4*)(send + e);
    int r, s, pos;
    r = rv.x; s = sv.x; pos = atomicAdd(&cnt[r], 1); if (pos < PADC) es[r * PADC + pos] = (u16)s;
    r = rv.y; s = sv.y; pos = atomicAdd(&cnt[r], 1); if (pos < PADC) es[r * PADC + pos] = (u16)s;
    r = rv.z; s = sv.z; pos = atomicAdd(&cnt[r], 1); if (pos < PADC) es[r * PADC + pos] = (u16)s;
    r = rv.w; s = sv.w; pos = atomicAdd(&cnt[r], 1); if (pos < PADC) es[r * PADC + pos] = (u16)s;
}

// ---- K3: bf16 MFMA GEMM from f32 h, C = h @ {W|Wq|Wk} (+bias), out bf16 ----
__global__ __launch_bounds__(256) void gemm_k(
    const float* __restrict__ h, const u16* __restrict__ wt,
    const float* __restrict__ bq, const float* __restrict__ bk,
    u16* __restrict__ hproj, u16* __restrict__ qbuf, u16* __restrict__ kbuf) {
    int g = blockIdx.x;
    int wave = threadIdx.x >> 6, lane = threadIdx.x & 63;
    int lm = lane & 15, lq = lane >> 4;
    int bx = g & 127, by = g >> 7;          // by in [0,12); XCD = g%8 = bx%8 (same rows stay on one XCD across by)
    int m0 = bx * 64 + wave * 16;
    int region = by >> 2, n0b = (by & 3) * 64;
    const u16* wtr = wt + region * 65536;

    v4f acc[4];
#pragma unroll
    for (int nt = 0; nt < 4; nt++) acc[nt] = (v4f){0.f, 0.f, 0.f, 0.f};

    const float* arow = h + (m0 + lm) * 256 + lq * 8;
#pragma unroll
    for (int k0 = 0; k0 < 256; k0 += 32) {
        float4 f0 = *(const float4*)(arow + k0);
        float4 f1 = *(const float4*)(arow + k0 + 4);
        v8s a;
        a[0] = (short)f2bf(f0.x); a[1] = (short)f2bf(f0.y);
        a[2] = (short)f2bf(f0.z); a[3] = (short)f2bf(f0.w);
        a[4] = (short)f2bf(f1.x); a[5] = (short)f2bf(f1.y);
        a[6] = (short)f2bf(f1.z); a[7] = (short)f2bf(f1.w);
#pragma unroll
        for (int nt = 0; nt < 4; nt++) {
            v8s bb = *(const v8s*)(wtr + (n0b + nt * 16 + lm) * 256 + k0 + lq * 8);
            acc[nt] = __builtin_amdgcn_mfma_f32_16x16x32_bf16(a, bb, acc[nt], 0, 0, 0);
        }
    }
    u16* outp = (region == 0) ? hproj : ((region == 1) ? qbuf : kbuf);
    const float* bias = (region == 1) ? bq : ((region == 2) ? bk : nullptr);
#pragma unroll
    for (int nt = 0; nt < 4; nt++) {
        int nn = n0b + nt * 16 + lm;
        float bv = bias ? bias[nn] : 0.f;
#pragma unroll
        for (int i = 0; i < 4; i++) {
            int m = m0 + lq * 4 + i;
            outp[m * 256 + nn] = f2bf(acc[nt][i] + bv);
        }
    }
}

// ---- K4: edge kernel, VALU dot + butterfly reduce. 8 edges/iter (4 per half). ----
// No VGPR cap that forces spills this time: live set ~90 regs under a 128 budget.
#define DOT_AGG(SIDX) do {                                                    \
    int off_ = (int)(SIDX) * 256 + cb;                                        \
    uint4 qv_ = *(const uint4*)(qbuf + off_);                                 \
    uint4 hv_ = *(const uint4*)(hpb + off_);                                  \
    float p_ = kr0 * bflo(qv_.x) + kr1 * bfhi(qv_.x)                          \
             + kr2 * bflo(qv_.y) + kr3 * bfhi(qv_.y)                          \
             + kr4 * bflo(qv_.z) + kr5 * bfhi(qv_.z)                          \
             + kr6 * bflo(qv_.w) + kr7 * bfhi(qv_.w);                         \
    p_ += __shfl_xor(p_, 1, 32);                                              \
    p_ += __shfl_xor(p_, 2, 32);                                              \
    p_ += __shfl_xor(p_, 4, 32);                                              \
    p_ += __shfl_xor(p_, 8, 32);                                              \
    p_ += __shfl_xor(p_, 16, 32);                                             \
    a0 += p_ * bflo(hv_.x); a1 += p_ * bfhi(hv_.x);                           \
    a2 += p_ * bflo(hv_.y); a3 += p_ * bfhi(hv_.y);                           \
    a4 += p_ * bflo(hv_.z); a5 += p_ * bfhi(hv_.z);                           \
    a6 += p_ * bflo(hv_.w); a7 += p_ * bfhi(hv_.w);                           \
} while (0)

__global__ __launch_bounds__(256, 4) void edge_fused(
    const u16* __restrict__ qbuf, const u16* __restrict__ kbuf,
    const u16* __restrict__ hpb, const int* __restrict__ cnt,
    const u16* __restrict__ es, float* __restrict__ out) {
    int wave = threadIdx.x >> 6, lane = threadIdx.x & 63;
    int r = blockIdx.x * 4 + wave;
    int lh = lane & 31, half = lane >> 5;
    int cb = lh * 8;
    int n = min(cnt[r], PADC);
    int base = r * PADC;

    // unpack k[r] segment (this lane's 8 columns), hoisted
    uint4 kv = *(const uint4*)(kbuf + r * 256 + cb);
    float kr0 = bflo(kv.x), kr1 = bfhi(kv.x), kr2 = bflo(kv.y), kr3 = bfhi(kv.y),
          kr4 = bflo(kv.z), kr5 = bfhi(kv.z), kr6 = bflo(kv.w), kr7 = bfhi(kv.w);

    float a0 = 0.f, a1 = 0.f, a2 = 0.f, a3 = 0.f,
          a4 = 0.f, a5 = 0.f, a6 = 0.f, a7 = 0.f;

    // prefetched uniform sender pack: 4 u16 senders for this half's sub-tile
    uint2 sp = *(const uint2*)(es + base + half * 4);
    for (int c0 = 0; c0 < n; c0 += 8) {
        int nx = c0 + 8;
        uint2 spn = sp;
        if (nx < n) spn = *(const uint2*)(es + base + nx + half * 4);

        if (nx <= n) {
            // full tile: 4 unguarded edges per half, loads pipeline freely
            DOT_AGG(sp.x & 0xffffu);
            DOT_AGG(sp.x >> 16);
            DOT_AGG(sp.y & 0xffffu);
            DOT_AGG(sp.y >> 16);
        } else {
            int mrem = n - c0 - half * 4;     // uniform per half; may be <= 0
            if (mrem > 0) DOT_AGG(sp.x & 0xffffu);
            if (mrem > 1) DOT_AGG(sp.x >> 16);
            if (mrem > 2) DOT_AGG(sp.y & 0xffffu);
            if (mrem > 3) DOT_AGG(sp.y >> 16);
        }
        sp = spn;
    }

    // combine halves (same columns, disjoint edge sets)
    a0 += __shfl_xor(a0, 32, 64); a1 += __shfl_xor(a1, 32, 64);
    a2 += __shfl_xor(a2, 32, 64); a3 += __shfl_xor(a3, 32, 64);
    a4 += __shfl_xor(a4, 32, 64); a5 += __shfl_xor(a5, 32, 64);
    a6 += __shfl_xor(a6, 32, 64); a7 += __shfl_xor(a7, 32, 64);

    if (half == 0) {
        float4 o0, o1;
        o0.x = fmaxf(a0, 0.f); o0.y = fmaxf(a1, 0.f);
        o0.z = fmaxf(a2, 0.f); o0.w = fmaxf(a3, 0.f);
        o1.x = fmaxf(a4, 0.f); o1.y = fmaxf(a5, 0.f);
        o1.z = fmaxf(a6, 0.f); o1.w = fmaxf(a7, 0.f);
        float* op = out + r * 256 + cb;
        *(float4*)op = o0;
        *(float4*)(op + 4) = o1;
    }
}

extern "C" void kernel_launch(void* const* d_in, const int* in_sizes, int n_in,
                              void* d_out, int out_size, void* d_ws, size_t ws_size,
                              hipStream_t stream) {
    const float* h  = (const float*)d_in[0];
    const float* W  = (const float*)d_in[1];
    const float* Wq = (const float*)d_in[2];
    const float* bq = (const float*)d_in[3];
    const float* Wk = (const float*)d_in[4];
    const float* bk = (const float*)d_in[5];
    const int* senders   = (const int*)d_in[6];
    const int* receivers = (const int*)d_in[7];
    float* out = (float*)d_out;

    char* ws = (char*)d_ws;
    u16* wt    = (u16*)ws;                        // 3*65536*2 = 384 KB
    u16* hproj = (u16*)(ws + 393216);             // 4 MB
    u16* qbuf  = hproj + N_NODES * DFEAT;         // 4 MB
    u16* kbuf  = qbuf + N_NODES * DFEAT;          // 4 MB
    int* cnt   = (int*)(kbuf + N_NODES * DFEAT);  // 32 KB
    u16* es    = (u16*)(cnt + N_NODES);           // 8192*160*2 = 2.56 MB

    prep_small<<<56, 256, 0, stream>>>(W, Wq, Wk, wt, cnt);
    scatter_k<<<512, 256, 0, stream>>>(receivers, senders, cnt, es);
    gemm_k<<<1536, 256, 0, stream>>>(h, wt, bq, bk, hproj, qbuf, kbuf);
    edge_fused<<<N_NODES / 4, 256, 0, stream>>>(qbuf, kbuf, hproj, cnt, es, out);
}

// Round 3
// 182.219 us; speedup vs baseline: 1.5866x; 1.0267x over previous
//
#include <hip/hip_runtime.h>
#include <stdint.h>

typedef unsigned short u16;
typedef unsigned int u32;
typedef short v8s __attribute__((ext_vector_type(8)));
typedef float v4f __attribute__((ext_vector_type(4)));

#define N_NODES 8192
#define N_EDGES 524288
#define DFEAT 256
#define PADC 160   // per-receiver bucket capacity; deg ~ Bin(524288, 2^-13): mean 64, sigma 8

static __device__ __forceinline__ float bflo(u32 u) { return __uint_as_float(u << 16); }
static __device__ __forceinline__ float bfhi(u32 u) { return __uint_as_float(u & 0xffff0000u); }
static __device__ __forceinline__ u16 f2bf(float f) {
    u32 u = __float_as_uint(f);
    return (u16)((u + 0x7fffu + ((u >> 16) & 1u)) >> 16);
}

// ---- K1 (tiny): W transpose -> bf16 wt (48 blocks) + cnt zeroing (8 blocks) ----
__global__ void prep_small(const float* __restrict__ w0, const float* __restrict__ w1,
                           const float* __restrict__ w2, u16* __restrict__ wt,
                           int* __restrict__ cnt) {
    int b = blockIdx.x;
    if (b < 48) {
        __shared__ u16 t[64][65];
        int region = b >> 4, tile = b & 15;
        int k0 = (tile >> 2) * 64, n0 = (tile & 3) * 64;
        const float* w = (region == 0) ? w0 : ((region == 1) ? w1 : w2);
        int tx = threadIdx.x & 63, ty = threadIdx.x >> 6;
#pragma unroll
        for (int it = 0; it < 16; it++) {
            int row = it * 4 + ty;
            t[row][tx] = f2bf(w[(k0 + row) * 256 + n0 + tx]);
        }
        __syncthreads();
        u16* o = wt + region * 65536;
#pragma unroll
        for (int it = 0; it < 16; it++) {
            int row = it * 4 + ty;
            o[(n0 + row) * 256 + k0 + tx] = t[tx][row];
        }
    } else {
        int i = ((b - 48) * 256 + threadIdx.x) * 4;
        *(int4*)(cnt + i) = make_int4(0, 0, 0, 0);
    }
}

// ---- K2: scatter (blocks 0..2047, 1 edge/thread — no serial atomic chain) ----
// ----     + bf16 MFMA GEMM from f32 h (blocks 2048..3583)                   ----
__global__ __launch_bounds__(256) void main_mid(
    const float* __restrict__ h, const u16* __restrict__ wt,
    const float* __restrict__ bq, const float* __restrict__ bk,
    const int* __restrict__ recv, const int* __restrict__ send,
    u16* __restrict__ hproj, u16* __restrict__ qbuf, u16* __restrict__ kbuf,
    int* __restrict__ cnt, u16* __restrict__ es) {
    int b = blockIdx.x;
    if (b < 2048) {
        int e = b * 256 + threadIdx.x;
        int r = recv[e];
        int s = send[e];
        int pos = atomicAdd(&cnt[r], 1);
        if (pos < PADC) es[r * PADC + pos] = (u16)s;
    } else {
        int g = b - 2048;
        int wave = threadIdx.x >> 6, lane = threadIdx.x & 63;
        int lm = lane & 15, lq = lane >> 4;
        int bx = g & 127, by = g >> 7;          // by in [0,12)
        int m0 = bx * 64 + wave * 16;
        int region = by >> 2, n0b = (by & 3) * 64;
        const u16* wtr = wt + region * 65536;

        v4f acc[4];
#pragma unroll
        for (int nt = 0; nt < 4; nt++) acc[nt] = (v4f){0.f, 0.f, 0.f, 0.f};

        const float* arow = h + (m0 + lm) * 256 + lq * 8;
#pragma unroll
        for (int k0 = 0; k0 < 256; k0 += 32) {
            float4 f0 = *(const float4*)(arow + k0);
            float4 f1 = *(const float4*)(arow + k0 + 4);
            v8s a;
            a[0] = (short)f2bf(f0.x); a[1] = (short)f2bf(f0.y);
            a[2] = (short)f2bf(f0.z); a[3] = (short)f2bf(f0.w);
            a[4] = (short)f2bf(f1.x); a[5] = (short)f2bf(f1.y);
            a[6] = (short)f2bf(f1.z); a[7] = (short)f2bf(f1.w);
#pragma unroll
            for (int nt = 0; nt < 4; nt++) {
                v8s bb = *(const v8s*)(wtr + (n0b + nt * 16 + lm) * 256 + k0 + lq * 8);
                acc[nt] = __builtin_amdgcn_mfma_f32_16x16x32_bf16(a, bb, acc[nt], 0, 0, 0);
            }
        }
        u16* outp = (region == 0) ? hproj : ((region == 1) ? qbuf : kbuf);
        const float* bias = (region == 1) ? bq : ((region == 2) ? bk : nullptr);
#pragma unroll
        for (int nt = 0; nt < 4; nt++) {
            int nn = n0b + nt * 16 + lm;
            float bv = bias ? bias[nn] : 0.f;
#pragma unroll
            for (int i = 0; i < 4; i++) {
                int m = m0 + lq * 4 + i;
                outp[m * 256 + nn] = f2bf(acc[nt][i] + bv);
            }
        }
    }
}

// ---- K3: edge kernel, explicit batched-gather ILP ----
// half-wave (32 lanes x 8 cols) per edge, 4 edges per half per iter.
// Phase structure: issue all 8 gathers -> 4 independent dots -> 4 interleaved
// butterflies (depth 5, ILP 4) -> 4 axpys. No LDS, no MFMA, no fence.

#define DOT8(Q) (kr0 * bflo((Q).x) + kr1 * bfhi((Q).x)                        \
               + kr2 * bflo((Q).y) + kr3 * bfhi((Q).y)                        \
               + kr4 * bflo((Q).z) + kr5 * bfhi((Q).z)                        \
               + kr6 * bflo((Q).w) + kr7 * bfhi((Q).w))

#define AXPY(P, H) do {                                                       \
    a0 += (P) * bflo((H).x); a1 += (P) * bfhi((H).x);                         \
    a2 += (P) * bflo((H).y); a3 += (P) * bfhi((H).y);                         \
    a4 += (P) * bflo((H).z); a5 += (P) * bfhi((H).z);                         \
    a6 += (P) * bflo((H).w); a7 += (P) * bfhi((H).w);                         \
} while (0)

// guarded single-edge path (tail only)
#define DOT_AGG1(SIDX) do {                                                   \
    int off_ = (int)(SIDX) * 256 + cb;                                        \
    uint4 qv_ = *(const uint4*)(qbuf + off_);                                 \
    uint4 hv_ = *(const uint4*)(hpb + off_);                                  \
    float p_ = DOT8(qv_);                                                     \
    p_ += __shfl_xor(p_, 1, 32);  p_ += __shfl_xor(p_, 2, 32);                \
    p_ += __shfl_xor(p_, 4, 32);  p_ += __shfl_xor(p_, 8, 32);                \
    p_ += __shfl_xor(p_, 16, 32);                                             \
    AXPY(p_, hv_);                                                            \
} while (0)

__global__ __launch_bounds__(256, 4) void edge_fused(
    const u16* __restrict__ qbuf, const u16* __restrict__ kbuf,
    const u16* __restrict__ hpb, const int* __restrict__ cnt,
    const u16* __restrict__ es, float* __restrict__ out) {
    int wave = threadIdx.x >> 6, lane = threadIdx.x & 63;
    int r = blockIdx.x * 4 + wave;
    int lh = lane & 31, half = lane >> 5;
    int cb = lh * 8;
    int n = min(cnt[r], PADC);
    int base = r * PADC;

    uint4 kv = *(const uint4*)(kbuf + r * 256 + cb);
    float kr0 = bflo(kv.x), kr1 = bfhi(kv.x), kr2 = bflo(kv.y), kr3 = bfhi(kv.y),
          kr4 = bflo(kv.z), kr5 = bfhi(kv.z), kr6 = bflo(kv.w), kr7 = bfhi(kv.w);

    float a0 = 0.f, a1 = 0.f, a2 = 0.f, a3 = 0.f,
          a4 = 0.f, a5 = 0.f, a6 = 0.f, a7 = 0.f;

    uint2 sp = *(const uint2*)(es + base + half * 4);
    for (int c0 = 0; c0 < n; c0 += 8) {
        int nx = c0 + 8;
        uint2 spn = sp;
        if (nx < n) spn = *(const uint2*)(es + base + nx + half * 4);

        if (nx <= n) {
            int s0 = (int)(sp.x & 0xffffu), s1 = (int)(sp.x >> 16);
            int s2 = (int)(sp.y & 0xffffu), s3 = (int)(sp.y >> 16);
            int o0 = s0 * 256 + cb, o1 = s1 * 256 + cb;
            int o2 = s2 * 256 + cb, o3 = s3 * 256 + cb;
            // phase 1: issue all 8 gathers
            uint4 q0 = *(const uint4*)(qbuf + o0);
            uint4 q1 = *(const uint4*)(qbuf + o1);
            uint4 q2 = *(const uint4*)(qbuf + o2);
            uint4 q3 = *(const uint4*)(qbuf + o3);
            uint4 h0 = *(const uint4*)(hpb + o0);
            uint4 h1 = *(const uint4*)(hpb + o1);
            uint4 h2 = *(const uint4*)(hpb + o2);
            uint4 h3 = *(const uint4*)(hpb + o3);
            // phase 2: 4 independent partial dots
            float p0 = DOT8(q0);
            float p1 = DOT8(q1);
            float p2 = DOT8(q2);
            float p3 = DOT8(q3);
            // phase 3: 4 butterflies interleaved (depth 5, ILP 4)
            p0 += __shfl_xor(p0, 1, 32);  p1 += __shfl_xor(p1, 1, 32);
            p2 += __shfl_xor(p2, 1, 32);  p3 += __shfl_xor(p3, 1, 32);
            p0 += __shfl_xor(p0, 2, 32);  p1 += __shfl_xor(p1, 2, 32);
            p2 += __shfl_xor(p2, 2, 32);  p3 += __shfl_xor(p3, 2, 32);
            p0 += __shfl_xor(p0, 4, 32);  p1 += __shfl_xor(p1, 4, 32);
            p2 += __shfl_xor(p2, 4, 32);  p3 += __shfl_xor(p3, 4, 32);
            p0 += __shfl_xor(p0, 8, 32);  p1 += __shfl_xor(p1, 8, 32);
            p2 += __shfl_xor(p2, 8, 32);  p3 += __shfl_xor(p3, 8, 32);
            p0 += __shfl_xor(p0, 16, 32); p1 += __shfl_xor(p1, 16, 32);
            p2 += __shfl_xor(p2, 16, 32); p3 += __shfl_xor(p3, 16, 32);
            // phase 4: weighted accumulate
            AXPY(p0, h0);
            AXPY(p1, h1);
            AXPY(p2, h2);
            AXPY(p3, h3);
        } else {
            int mrem = n - c0 - half * 4;     // uniform per half; may be <= 0
            if (mrem > 0) DOT_AGG1(sp.x & 0xffffu);
            if (mrem > 1) DOT_AGG1(sp.x >> 16);
            if (mrem > 2) DOT_AGG1(sp.y & 0xffffu);
            if (mrem > 3) DOT_AGG1(sp.y >> 16);
        }
        sp = spn;
    }

    // combine halves (same columns, disjoint edge sets)
    a0 += __shfl_xor(a0, 32, 64); a1 += __shfl_xor(a1, 32, 64);
    a2 += __shfl_xor(a2, 32, 64); a3 += __shfl_xor(a3, 32, 64);
    a4 += __shfl_xor(a4, 32, 64); a5 += __shfl_xor(a5, 32, 64);
    a6 += __shfl_xor(a6, 32, 64); a7 += __shfl_xor(a7, 32, 64);

    if (half == 0) {
        float4 o0, o1;
        o0.x = fmaxf(a0, 0.f); o0.y = fmaxf(a1, 0.f);
        o0.z = fmaxf(a2, 0.f); o0.w = fmaxf(a3, 0.f);
        o1.x = fmaxf(a4, 0.f); o1.y = fmaxf(a5, 0.f);
        o1.z = fmaxf(a6, 0.f); o1.w = fmaxf(a7, 0.f);
        float* op = out + r * 256 + cb;
        *(float4*)op = o0;
        *(float4*)(op + 4) = o1;
    }
}

extern "C" void kernel_launch(void* const* d_in, const int* in_sizes, int n_in,
                              void* d_out, int out_size, void* d_ws, size_t ws_size,
                              hipStream_t stream) {
    const float* h  = (const float*)d_in[0];
    const float* W  = (const float*)d_in[1];
    const float* Wq = (const float*)d_in[2];
    const float* bq = (const float*)d_in[3];
    const float* Wk = (const float*)d_in[4];
    const float* bk = (const float*)d_in[5];
    const int* senders   = (const int*)d_in[6];
    const int* receivers = (const int*)d_in[7];
    float* out = (float*)d_out;

    char* ws = (char*)d_ws;
    u16* wt    = (u16*)ws;                        // 3*65536*2 = 384 KB
    u16* hproj = (u16*)(ws + 393216);             // 4 MB
    u16* qbuf  = hproj + N_NODES * DFEAT;         // 4 MB
    u16* kbuf  = qbuf + N_NODES * DFEAT;          // 4 MB
    int* cnt   = (int*)(kbuf + N_NODES * DFEAT);  // 32 KB
    u16* es    = (u16*)(cnt + N_NODES);           // 8192*160*2 = 2.56 MB

    prep_small<<<56, 256, 0, stream>>>(W, Wq, Wk, wt, cnt);
    main_mid<<<3584, 256, 0, stream>>>(h, wt, bq, bk, receivers, senders,
                                       hproj, qbuf, kbuf, cnt, es);
    edge_fused<<<N_NODES / 4, 256, 0, stream>>>(qbuf, kbuf, hproj, cnt, es, out);
}